// Round 3
// baseline (173.438 us; speedup 1.0000x reference)
//
#include <hip/hip_runtime.h>

#define NUM_LAYERS 1000
#define DIM 10
#define STRIDE 112           // floats per affine slot (10x11 = 110, padded to 112)
#define LPB 16               // layers per block in K1
#define NBLK 63              // ceil(1000/16)

// Affine stored col-major in a slot: slot[j*10 + r] = M[r][j] for j<10,
// slot[100 + r] = c[r] (i.e. column 10 of the 11x11 homogeneous matrix).
// Compose: dst = g(f(.)):  col_j(dst) = M_g * col_j(f)  (+ c_g when j==10).
__device__ inline void compose_one(const float* __restrict__ src,
                                   float* __restrict__ dst,
                                   int c, int lane) {
    const float* F = src + (size_t)(2 * c) * STRIDE;
    const float* G = src + (size_t)(2 * c + 1) * STRIDE;
    float colf[DIM], o[DIM];
    #pragma unroll
    for (int r = 0; r < DIM; ++r) colf[r] = F[lane * DIM + r];
    #pragma unroll
    for (int r = 0; r < DIM; ++r) {
        float acc = (lane == DIM) ? G[100 + r] : 0.f;
        #pragma unroll
        for (int k = 0; k < DIM; ++k)
            acc += G[k * DIM + r] * colf[k];
        o[r] = acc;
    }
    float* D = dst + (size_t)c * STRIDE;
    #pragma unroll
    for (int r = 0; r < DIM; ++r) D[lane * DIM + r] = o[r];
}

// ---------------------------------------------------------------------------
// K1: block b composes layers [b*16, b*16+16) (identity-padded past 999) via
// a 4-level LDS tree: 16 -> 8 -> 4 -> 2 -> 1. One wave per compose.
// ---------------------------------------------------------------------------
__global__ __launch_bounds__(1024) void compose16(const float* __restrict__ Ws,
                                                  const float* __restrict__ bs,
                                                  float* __restrict__ wsout) {
    __shared__ float A[LPB * STRIDE];
    __shared__ float B[(LPB / 2) * STRIDE];
    const int tid = threadIdx.x;
    const int blk = blockIdx.x;

    for (int e = tid; e < LPB * 100; e += 1024) {
        int ll = e / 100, rem = e % 100;      // rem = r*10 + k
        int r = rem / 10, k = rem % 10;
        int l = blk * LPB + ll;
        float v = (l < NUM_LAYERS) ? Ws[(size_t)l * 100 + rem]
                                   : (r == k ? 1.f : 0.f);
        A[ll * STRIDE + k * DIM + r] = v;
    }
    for (int e = tid; e < LPB * DIM; e += 1024) {
        int ll = e / DIM, r = e % DIM;
        int l = blk * LPB + ll;
        float v = (l < NUM_LAYERS) ? bs[(size_t)l * DIM + r] : 0.f;
        A[ll * STRIDE + 100 + r] = v;
    }

    const int wave = tid >> 6, lane = tid & 63;
    const float* src = A;
    float* dst = B;
    for (int n = LPB / 2; n >= 1; n >>= 1) {   // n = 8,4,2,1
        __syncthreads();
        if (wave < n && lane <= DIM) compose_one(src, dst, wave, lane);
        const float* t = dst; dst = (float*)src; src = t;
    }
    __syncthreads();
    if (tid < 110) wsout[(size_t)blk * STRIDE + tid] = A[tid];
}

// ---------------------------------------------------------------------------
// K2: one block folds the 63 chunk affines (padded to 64 with identity) via a
// 6-level LDS tree. Writes the final affine ROW-major:
// aff[r*10+k] = M[r][k], aff[100+r] = c[r].
// ---------------------------------------------------------------------------
__global__ __launch_bounds__(1024) void compose_tree64(const float* __restrict__ wsin,
                                                       float* __restrict__ aff) {
    __shared__ float A[64 * STRIDE];
    __shared__ float B[32 * STRIDE];
    const int tid = threadIdx.x;

    for (int e = tid; e < 64 * STRIDE; e += 1024) {
        int chunk = e / STRIDE, pos = e % STRIDE;
        float v;
        if (pos >= 110)        v = 0.f;
        else if (chunk < NBLK) v = wsin[(size_t)chunk * STRIDE + pos];
        else v = (pos < 100 && (pos / 10 == pos % 10)) ? 1.f : 0.f;  // identity
        A[e] = v;
    }

    const int wave = tid >> 6, lane = tid & 63;
    const float* src = A;
    float* dst = B;
    for (int n = 32; n >= 1; n >>= 1) {        // n = 32,16,8,4,2,1
        __syncthreads();
        if (lane <= DIM)
            for (int c = wave; c < n; c += 16)
                compose_one(src, dst, c, lane);
        const float* t = dst; dst = (float*)src; src = t;
    }
    __syncthreads();
    if (tid < 110) {
        if (tid < 100) {
            int j = tid / DIM, r = tid % DIM;  // A[j*10+r] = M[r][j]
            aff[r * DIM + j] = A[tid];
        } else {
            aff[tid] = A[tid];                 // bias
        }
    }
}

// ---------------------------------------------------------------------------
// K3: out = M x + c. Two rows/thread -> 80 B = 5 x float4 per direction.
// The affine is read via WAVE-UNIFORM loads with NO divergent control
// dependence -> backend scalarizes to s_load -> SGPRs. v_fmac reads one SGPR
// per op (legal), so the hot loop is pure VALU + VMEM: zero LDS, HBM-bound.
// Per-j blocking keeps only 11 scalars live at a time (SGPR budget ~102).
// ---------------------------------------------------------------------------
__global__ __launch_bounds__(256) void apply_affine(const float* __restrict__ x,
                                                    const float* __restrict__ aff,
                                                    float* __restrict__ out,
                                                    int npairs) {
    const int t = blockIdx.x * blockDim.x + threadIdx.x;
    const bool act = (t < npairs);

    float xv[20] = {};
    if (act) {
        const float4* xin = (const float4*)x + (size_t)t * 5;
        float4 v0 = xin[0], v1 = xin[1], v2 = xin[2], v3 = xin[3], v4 = xin[4];
        xv[0]=v0.x;  xv[1]=v0.y;  xv[2]=v0.z;  xv[3]=v0.w;
        xv[4]=v1.x;  xv[5]=v1.y;  xv[6]=v1.z;  xv[7]=v1.w;
        xv[8]=v2.x;  xv[9]=v2.y;  xv[10]=v2.z; xv[11]=v2.w;
        xv[12]=v3.x; xv[13]=v3.y; xv[14]=v3.z; xv[15]=v3.w;
        xv[16]=v4.x; xv[17]=v4.y; xv[18]=v4.z; xv[19]=v4.w;
    }

    float o[20];
    #pragma unroll
    for (int j = 0; j < DIM; ++j) {
        // Uniform loads, unconditional -> s_load; short live range per j.
        const float b = aff[100 + j];
        float a[DIM];
        #pragma unroll
        for (int k = 0; k < DIM; ++k) a[k] = aff[j * DIM + k];
        float acc0 = b, acc1 = b;
        #pragma unroll
        for (int k = 0; k < DIM; ++k) {
            acc0 += a[k] * xv[k];
            acc1 += a[k] * xv[DIM + k];
        }
        o[j] = acc0;
        o[DIM + j] = acc1;
    }

    if (act) {
        float4* op = (float4*)out + (size_t)t * 5;
        op[0] = make_float4(o[0],  o[1],  o[2],  o[3]);
        op[1] = make_float4(o[4],  o[5],  o[6],  o[7]);
        op[2] = make_float4(o[8],  o[9],  o[10], o[11]);
        op[3] = make_float4(o[12], o[13], o[14], o[15]);
        op[4] = make_float4(o[16], o[17], o[18], o[19]);
    }
}

extern "C" void kernel_launch(void* const* d_in, const int* in_sizes, int n_in,
                              void* d_out, int out_size, void* d_ws, size_t ws_size,
                              hipStream_t stream) {
    const float* x  = (const float*)d_in[0];   // [BATCH, 10]
    const float* Ws = (const float*)d_in[1];   // [1000, 10, 10]
    const float* bs = (const float*)d_in[2];   // [1000, 10]
    float* out = (float*)d_out;

    float* ws_chunks = (float*)d_ws;                      // NBLK * STRIDE floats
    float* ws_aff    = ws_chunks + NBLK * STRIDE;         // 110 floats

    const int batch  = in_sizes[0] / DIM;
    const int npairs = batch / 2;

    compose16<<<NBLK, 1024, 0, stream>>>(Ws, bs, ws_chunks);
    compose_tree64<<<1, 1024, 0, stream>>>(ws_chunks, ws_aff);

    const int threads = 256;
    const int blocks  = (npairs + threads - 1) / threads;
    apply_affine<<<blocks, threads, 0, stream>>>(x, ws_aff, out, npairs);
}